// Round 10
// baseline (373.682 us; speedup 1.0000x reference)
//
#include <hip/hip_runtime.h>
#include <hip/hip_fp16.h>
#include <math.h>

#define N_NODES 100000
#define N_EDGES 1600000
#define IN_FEAT 128
#define HIDDEN 64
#define N_CLASSES 16

#define TM 64
#define GBLK ((N_NODES + TM - 1) / TM)  // 1563

#define NBUK 196                        // buckets of 512 nodes (dst>>9)
#define CB 4096                         // edges per coarse block
#define NCB ((N_EDGES + CB - 1) / CB)   // 391
#define EPB 1024                        // edges per bukhist block
#define NHB ((N_EDGES + EPB - 1) / EPB) // 1563

// ---------------- bucket histogram (LDS, tiny global flush) ----------------

__global__ void zero_buk_k(int* __restrict__ buk_cnt) {
    if (threadIdx.x < NBUK + 4) buk_cnt[threadIdx.x] = 0;
}

__global__ __launch_bounds__(256) void bukhist_k(const int* __restrict__ dst,
                                                 int* __restrict__ buk_cnt) {
    __shared__ int hist[NBUK + 4];
    int tid = threadIdx.x;
    if (tid < NBUK) hist[tid] = 0;
    __syncthreads();
    int base = blockIdx.x * EPB + tid * 4;
    if (base < N_EDGES) {  // N_EDGES % 4 == 0
        int4 d4 = ((const int4*)dst)[base >> 2];
        atomicAdd(&hist[d4.x >> 9], 1);
        atomicAdd(&hist[d4.y >> 9], 1);
        atomicAdd(&hist[d4.z >> 9], 1);
        atomicAdd(&hist[d4.w >> 9], 1);
    }
    __syncthreads();
    if (tid < NBUK && hist[tid] != 0) atomicAdd(&buk_cnt[tid], hist[tid]);
}

// scan 196 bucket counts -> buk_off (exclusive), init bcur
__global__ __launch_bounds__(256) void buk_scan_k(const int* __restrict__ buk_cnt,
                                                  int* __restrict__ buk_off,
                                                  int* __restrict__ bcur) {
    __shared__ int sm[256];
    int t = threadIdx.x;
    int v = (t < NBUK) ? buk_cnt[t] : 0;
    sm[t] = v;
    __syncthreads();
    for (int s = 1; s < 256; s <<= 1) {
        int add = (t >= s) ? sm[t - s] : 0;
        __syncthreads();
        sm[t] += add;
        __syncthreads();
    }
    if (t < NBUK) {
        int excl = sm[t] - v;
        buk_off[t] = excl;
        bcur[t] = excl;
    }
    if (t == 0) buk_off[NBUK] = N_EDGES;
}

// ---------------- coarse partition: group edges by 512-node bucket ----------------

__global__ __launch_bounds__(256) void coarse_k(const int* __restrict__ src,
                                                const int* __restrict__ dst,
                                                int* __restrict__ bcur,
                                                int2* __restrict__ pairs) {
    __shared__ int hist[NBUK + 4], loff[NBUK + 4], cur[NBUK + 4], gbase[NBUK + 4];
    __shared__ int sc[256];
    __shared__ int2 stage[CB];  // 32 KB
    int tid = threadIdx.x;
    int eb = blockIdx.x * CB;
    int nvalid = N_EDGES - eb;
    if (nvalid > CB) nvalid = CB;

    if (tid < NBUK) hist[tid] = 0;
    __syncthreads();

    int4 s4[4], d4[4];
    #pragma unroll
    for (int q = 0; q < 4; ++q) {
        int e4 = (eb >> 2) + tid + q * 256;
        if (e4 * 4 < N_EDGES) {
            s4[q] = ((const int4*)src)[e4];
            d4[q] = ((const int4*)dst)[e4];
        } else {
            d4[q] = make_int4(-1, -1, -1, -1);
            s4[q] = make_int4(0, 0, 0, 0);
        }
    }
    #pragma unroll
    for (int q = 0; q < 4; ++q) {
        if (d4[q].x >= 0) {
            atomicAdd(&hist[d4[q].x >> 9], 1);
            atomicAdd(&hist[d4[q].y >> 9], 1);
            atomicAdd(&hist[d4[q].z >> 9], 1);
            atomicAdd(&hist[d4[q].w >> 9], 1);
        }
    }
    __syncthreads();

    int v = (tid < NBUK) ? hist[tid] : 0;
    sc[tid] = v;
    __syncthreads();
    for (int s = 1; s < 256; s <<= 1) {
        int add = (tid >= s) ? sc[tid - s] : 0;
        __syncthreads();
        sc[tid] += add;
        __syncthreads();
    }
    if (tid < NBUK) {
        int excl = sc[tid] - v;
        loff[tid] = excl;
        cur[tid] = excl;
        gbase[tid] = atomicAdd(&bcur[tid], v);
    }
    __syncthreads();

    #pragma unroll
    for (int q = 0; q < 4; ++q) {
        if (d4[q].x >= 0) {
            int b, r;
            b = d4[q].x >> 9; r = atomicAdd(&cur[b], 1); stage[r] = make_int2(s4[q].x, d4[q].x);
            b = d4[q].y >> 9; r = atomicAdd(&cur[b], 1); stage[r] = make_int2(s4[q].y, d4[q].y);
            b = d4[q].z >> 9; r = atomicAdd(&cur[b], 1); stage[r] = make_int2(s4[q].z, d4[q].z);
            b = d4[q].w >> 9; r = atomicAdd(&cur[b], 1); stage[r] = make_int2(s4[q].w, d4[q].w);
        }
    }
    __syncthreads();

    for (int i = tid; i < nvalid; i += 256) {
        int2 p = stage[i];
        int b = p.y >> 9;
        pairs[gbase[b] + (i - loff[b])] = p;
    }
}

// ---------------- fine: per-bucket degree count (LDS) + dinv + row_ptr + placement ----------------

__global__ __launch_bounds__(256) void fine2_k(const int2* __restrict__ pairs,
                                               const int* __restrict__ buk_off,
                                               int* __restrict__ csr_src,
                                               int* __restrict__ row_ptr,
                                               float* __restrict__ dinv) {
    __shared__ int cnt[512];
    __shared__ int psc[256];
    __shared__ int cur[512];
    int b = blockIdx.x;
    int node0 = b * 512;
    int nn = N_NODES - node0;
    if (nn > 512) nn = 512;
    int tid = threadIdx.x;

    cnt[tid] = 0; cnt[tid + 256] = 0;
    __syncthreads();

    int e0 = buk_off[b];
    int e1 = buk_off[b + 1];

    for (int e = e0 + tid; e < e1; e += 256)
        atomicAdd(&cnt[pairs[e].y - node0], 1);
    __syncthreads();

    int c0 = cnt[2 * tid], c1 = cnt[2 * tid + 1];
    int p = c0 + c1;
    psc[tid] = p;
    __syncthreads();
    for (int s = 1; s < 256; s <<= 1) {
        int add = (tid >= s) ? psc[tid - s] : 0;
        __syncthreads();
        psc[tid] += add;
        __syncthreads();
    }
    int excl = psc[tid] - p;
    int g0 = e0 + excl;
    int g1 = g0 + c0;
    cur[2 * tid] = g0;
    cur[2 * tid + 1] = g1;
    if (2 * tid < nn) {
        row_ptr[node0 + 2 * tid] = g0;
        dinv[node0 + 2 * tid] = 1.0f / sqrtf((float)(c0 + 1));
    }
    if (2 * tid + 1 < nn) {
        row_ptr[node0 + 2 * tid + 1] = g1;
        dinv[node0 + 2 * tid + 1] = 1.0f / sqrtf((float)(c1 + 1));
    }
    if (b == NBUK - 1 && tid == 0) row_ptr[N_NODES] = N_EDGES;
    __syncthreads();

    for (int e = e0 + tid; e < e1; e += 256) {
        int2 pr = pairs[e];
        int pos = atomicAdd(&cur[pr.y - node0], 1);
        csr_src[pos] = pr.x;
    }
}

// ---------------- register-tiled GEMM 1: hws_h = fp16((x @ W1) * dinv[row]) ----------------

__global__ __launch_bounds__(256) void gemm1_tiled_k(const float* __restrict__ x,
                                                     const float* __restrict__ W,
                                                     const float* __restrict__ dinv,
                                                     __half* __restrict__ hws_h) {
    __shared__ float Ws[64][64];
    __shared__ float xt[64][68];
    int tid = threadIdx.x;
    int row0 = blockIdx.x * TM;
    int rgrp4 = (tid >> 4) * 4;
    int cgrp4 = (tid & 15) * 4;

    float acc[4][4];
    #pragma unroll
    for (int r = 0; r < 4; ++r)
        #pragma unroll
        for (int c = 0; c < 4; ++c) acc[r][c] = 0.0f;

    for (int k0 = 0; k0 < IN_FEAT; k0 += 64) {
        #pragma unroll
        for (int i = 0; i < 4; ++i) {
            int f4 = tid + i * 256;
            int kk = f4 >> 4, c4 = (f4 & 15) * 4;
            *(float4*)&Ws[kk][c4] = *(const float4*)&W[(size_t)(k0 + kk) * HIDDEN + c4];
        }
        #pragma unroll
        for (int i = 0; i < 4; ++i) {
            int f4 = tid + i * 256;
            int rr = f4 >> 4, kq = (f4 & 15) * 4;
            int row = row0 + rr;
            if (row >= N_NODES) row = N_NODES - 1;
            float4 v = *(const float4*)&x[(size_t)row * IN_FEAT + k0 + kq];
            xt[kq + 0][rr] = v.x; xt[kq + 1][rr] = v.y;
            xt[kq + 2][rr] = v.z; xt[kq + 3][rr] = v.w;
        }
        __syncthreads();

        #pragma unroll 16
        for (int kk = 0; kk < 64; ++kk) {
            float4 a = *(const float4*)&xt[kk][rgrp4];
            float4 b = *(const float4*)&Ws[kk][cgrp4];
            acc[0][0] += a.x * b.x; acc[0][1] += a.x * b.y; acc[0][2] += a.x * b.z; acc[0][3] += a.x * b.w;
            acc[1][0] += a.y * b.x; acc[1][1] += a.y * b.y; acc[1][2] += a.y * b.z; acc[1][3] += a.y * b.w;
            acc[2][0] += a.z * b.x; acc[2][1] += a.z * b.y; acc[2][2] += a.z * b.z; acc[2][3] += a.z * b.w;
            acc[3][0] += a.w * b.x; acc[3][1] += a.w * b.y; acc[3][2] += a.w * b.z; acc[3][3] += a.w * b.w;
        }
        __syncthreads();
    }

    #pragma unroll
    for (int r = 0; r < 4; ++r) {
        int row = row0 + rgrp4 + r;
        if (row < N_NODES) {
            float dn = dinv[row];
            __half2* ph = (__half2*)&hws_h[(size_t)row * HIDDEN + cgrp4];
            ph[0] = __floats2half2_rn(acc[r][0] * dn, acc[r][1] * dn);
            ph[1] = __floats2half2_rn(acc[r][2] * dn, acc[r][3] * dn);
        }
    }
}

// ---------------- register-tiled GEMM 2: hws_h = fp16((relu(agg) @ W2) * dinv[row]) ----------------

__global__ __launch_bounds__(256) void gemm2_tiled_k(const float* __restrict__ agg,
                                                     const float* __restrict__ W,
                                                     const float* __restrict__ dinv,
                                                     __half* __restrict__ hws_h) {
    __shared__ float Ws[64][64];
    __shared__ float xt[64][68];
    int tid = threadIdx.x;
    int row0 = blockIdx.x * TM;
    int rgrp4 = (tid >> 4) * 4;
    int cgrp4 = (tid & 15) * 4;

    #pragma unroll
    for (int i = 0; i < 4; ++i) {
        int f4 = tid + i * 256;
        int kk = f4 >> 4, c4 = (f4 & 15) * 4;
        *(float4*)&Ws[kk][c4] = *(const float4*)&W[(size_t)kk * HIDDEN + c4];
    }
    #pragma unroll
    for (int i = 0; i < 4; ++i) {
        int f4 = tid + i * 256;
        int rr = f4 >> 4, kq = (f4 & 15) * 4;
        int row = row0 + rr;
        if (row >= N_NODES) row = N_NODES - 1;
        float4 v = *(const float4*)&agg[(size_t)row * HIDDEN + kq];
        xt[kq + 0][rr] = fmaxf(v.x, 0.f); xt[kq + 1][rr] = fmaxf(v.y, 0.f);
        xt[kq + 2][rr] = fmaxf(v.z, 0.f); xt[kq + 3][rr] = fmaxf(v.w, 0.f);
    }
    __syncthreads();

    float acc[4][4];
    #pragma unroll
    for (int r = 0; r < 4; ++r)
        #pragma unroll
        for (int c = 0; c < 4; ++c) acc[r][c] = 0.0f;

    #pragma unroll 16
    for (int kk = 0; kk < 64; ++kk) {
        float4 a = *(const float4*)&xt[kk][rgrp4];
        float4 b = *(const float4*)&Ws[kk][cgrp4];
        acc[0][0] += a.x * b.x; acc[0][1] += a.x * b.y; acc[0][2] += a.x * b.z; acc[0][3] += a.x * b.w;
        acc[1][0] += a.y * b.x; acc[1][1] += a.y * b.y; acc[1][2] += a.y * b.z; acc[1][3] += a.y * b.w;
        acc[2][0] += a.z * b.x; acc[2][1] += a.z * b.y; acc[2][2] += a.z * b.z; acc[2][3] += a.z * b.w;
        acc[3][0] += a.w * b.x; acc[3][1] += a.w * b.y; acc[3][2] += a.w * b.z; acc[3][3] += a.w * b.w;
    }

    #pragma unroll
    for (int r = 0; r < 4; ++r) {
        int row = row0 + rgrp4 + r;
        if (row < N_NODES) {
            float dn = dinv[row];
            __half2* ph = (__half2*)&hws_h[(size_t)row * HIDDEN + cgrp4];
            ph[0] = __floats2half2_rn(acc[r][0] * dn, acc[r][1] * dn);
            ph[1] = __floats2half2_rn(acc[r][2] * dn, acc[r][3] * dn);
        }
    }
}

// ---------------- CSR pull: agg[d] = b + dinv[d]*(hws[d] + sum_in hws[s]) ----------------
// one wave per node; 2 channels/lane (__half2), lanes 0-31 = edge A, 32-63 = edge B:
// one dword gather covers TWO edges. Wave-uniform index loads (s_load) + one cndmask.
// fp32 accumulation per channel; shfl_xor(32) merges halves; 32 lanes store float2.

__global__ __launch_bounds__(256) void pull_k(const int* __restrict__ row_ptr,
                                              const int* __restrict__ csr_src,
                                              const float* __restrict__ dinv,
                                              const __half* __restrict__ hws_h,
                                              const float* __restrict__ b,
                                              float* __restrict__ agg) {
    int node = (blockIdx.x * 256 + threadIdx.x) >> 6;
    int lane = threadIdx.x & 63;
    int hid  = lane >> 5;   // 0 -> even edge of pair, 1 -> odd edge
    int cl   = lane & 31;   // channel pair: channels 2cl, 2cl+1
    if (node >= N_NODES) return;

    const __half2* h2 = (const __half2*)hws_h;  // row stride = 32 half2

    int start = row_ptr[node];
    int end   = row_ptr[node + 1];

    float ax0 = 0.f, ay0 = 0.f, ax1 = 0.f, ay1 = 0.f;
    {   // self-loop term, added once (half 0)
        __half2 v = h2[(size_t)node * 32 + cl];
        if (hid == 0) { ax0 = __half2float(v.x); ay0 = __half2float(v.y); }
    }

    int i = start;
    for (; i + 16 <= end; i += 16) {
        #pragma unroll
        for (int j = 0; j < 8; ++j) {
            int s0 = csr_src[i + 2 * j];       // wave-uniform -> s_load
            int s1 = csr_src[i + 2 * j + 1];   // wave-uniform -> s_load
            int s = hid ? s1 : s0;             // one cndmask
            __half2 v = h2[(size_t)s * 32 + cl];
            if (j & 1) { ax1 += __half2float(v.x); ay1 += __half2float(v.y); }
            else       { ax0 += __half2float(v.x); ay0 += __half2float(v.y); }
        }
    }
    for (; i + 2 <= end; i += 2) {
        int s0 = csr_src[i];
        int s1 = csr_src[i + 1];
        int s = hid ? s1 : s0;
        __half2 v = h2[(size_t)s * 32 + cl];
        ax0 += __half2float(v.x); ay0 += __half2float(v.y);
    }
    if (i < end) {  // single leftover edge: half 0 only
        int s = csr_src[i];
        __half2 v = h2[(size_t)s * 32 + cl];
        if (hid == 0) { ax0 += __half2float(v.x); ay0 += __half2float(v.y); }
    }

    float ax = ax0 + ax1;
    float ay = ay0 + ay1;
    ax += __shfl_xor(ax, 32, 64);  // merge edge-halves (same channels)
    ay += __shfl_xor(ay, 32, 64);

    if (hid == 0) {
        float dn = dinv[node];
        float2 bb = ((const float2*)b)[cl];
        float2 o;
        o.x = bb.x + dn * ax;
        o.y = bb.y + dn * ay;
        ((float2*)agg)[(size_t)node * 32 + cl] = o;
    }
}

// ---------------- final: out = relu(agg) @ Wl + bl ----------------

__global__ __launch_bounds__(256) void final_k(const float* __restrict__ agg,
                                               const float* __restrict__ Wl,
                                               const float* __restrict__ bl,
                                               float* __restrict__ out) {
    __shared__ float Ws[HIDDEN * N_CLASSES];
    __shared__ float hs[16][HIDDEN + 1];
    int tid = threadIdx.x;

    if (tid < HIDDEN * N_CLASSES / 4) ((float4*)Ws)[tid] = ((const float4*)Wl)[tid];

    int row0 = blockIdx.x * 16;
    for (int i = tid; i < 16 * HIDDEN; i += 256) {
        int rr = i >> 6;
        int kk = i & 63;
        hs[rr][kk] = fmaxf(agg[(size_t)(row0 + rr) * HIDDEN + kk], 0.0f);
    }
    __syncthreads();

    int col = tid & 15;
    int r = tid >> 4;
    float acc = bl[col];
    #pragma unroll
    for (int k = 0; k < HIDDEN; ++k)
        acc += hs[r][k] * Ws[k * N_CLASSES + col];
    out[(size_t)(row0 + r) * N_CLASSES + col] = acc;
}

// ---------------- launch ----------------

extern "C" void kernel_launch(void* const* d_in, const int* in_sizes, int n_in,
                              void* d_out, int out_size, void* d_ws, size_t ws_size,
                              hipStream_t stream) {
    const float* x  = (const float*)d_in[0];
    const int*   ei = (const int*)d_in[1];
    const float* W1 = (const float*)d_in[2];
    const float* b1 = (const float*)d_in[3];
    const float* W2 = (const float*)d_in[4];
    const float* b2 = (const float*)d_in[5];
    const float* Wl = (const float*)d_in[6];
    const float* bl = (const float*)d_in[7];
    float* out = (float*)d_out;

    const int* src = ei;
    const int* dst = ei + N_EDGES;

    __half* hws_h  = (__half*)d_ws;                              // N*64 halves (12.8 MB)
    float* agg     = (float*)(hws_h + (size_t)N_NODES * HIDDEN); // N*64 floats (25.6 MB)
    int2*  pairs   = (int2*)agg;                                 // aliases agg (dead before pull writes agg)
    int*   csr_src = (int*)(agg + (size_t)N_NODES * HIDDEN);     // E
    float* dinv    = (float*)(csr_src + N_EDGES);                // N
    int*   row_ptr = (int*)(dinv + N_NODES);                     // N+4
    int*   buk_cnt = row_ptr + N_NODES + 4;                      // 200
    int*   buk_off = buk_cnt + 200;                              // 200
    int*   bcur    = buk_off + 200;                              // 200

    // --- CSR build (degree counting confined to LDS) ---
    zero_buk_k<<<1, 256, 0, stream>>>(buk_cnt);
    bukhist_k<<<NHB, 256, 0, stream>>>(dst, buk_cnt);
    buk_scan_k<<<1, 256, 0, stream>>>(buk_cnt, buk_off, bcur);
    coarse_k<<<NCB, 256, 0, stream>>>(src, dst, bcur, pairs);
    fine2_k<<<NBUK, 256, 0, stream>>>(pairs, buk_off, csr_src, row_ptr, dinv);

    // --- layer 1 ---
    gemm1_tiled_k<<<GBLK, 256, 0, stream>>>(x, W1, dinv, hws_h);
    pull_k<<<(N_NODES * 64 + 255) / 256, 256, 0, stream>>>(row_ptr, csr_src, dinv,
                                                           hws_h, b1, agg);

    // --- layer 2 ---
    gemm2_tiled_k<<<GBLK, 256, 0, stream>>>(agg, W2, dinv, hws_h);
    pull_k<<<(N_NODES * 64 + 255) / 256, 256, 0, stream>>>(row_ptr, csr_src, dinv,
                                                           hws_h, b2, agg);

    // --- classifier head ---
    final_k<<<N_NODES / 16, 256, 0, stream>>>(agg, Wl, bl, out);
}

// Round 11
// 342.863 us; speedup vs baseline: 1.0899x; 1.0899x over previous
//
#include <hip/hip_runtime.h>
#include <hip/hip_fp16.h>
#include <math.h>

#define N_NODES 100000
#define N_EDGES 1600000
#define IN_FEAT 128
#define HIDDEN 64
#define N_CLASSES 16

#define TM 64
#define GBLK ((N_NODES + TM - 1) / TM)  // 1563

#define NBUK 196                        // buckets of 512 nodes (dst>>9)
#define CB 4096                         // edges per coarse block
#define NCB ((N_EDGES + CB - 1) / CB)   // 391
#define EPB 1024                        // edges per bukhist block
#define NHB ((N_EDGES + EPB - 1) / EPB) // 1563

// ---------------- bucket histogram (LDS, tiny global flush) ----------------

__global__ void zero_buk_k(int* __restrict__ buk_cnt) {
    if (threadIdx.x < NBUK + 4) buk_cnt[threadIdx.x] = 0;
}

__global__ __launch_bounds__(256) void bukhist_k(const int* __restrict__ dst,
                                                 int* __restrict__ buk_cnt) {
    __shared__ int hist[NBUK + 4];
    int tid = threadIdx.x;
    if (tid < NBUK) hist[tid] = 0;
    __syncthreads();
    int base = blockIdx.x * EPB + tid * 4;
    if (base < N_EDGES) {  // N_EDGES % 4 == 0
        int4 d4 = ((const int4*)dst)[base >> 2];
        atomicAdd(&hist[d4.x >> 9], 1);
        atomicAdd(&hist[d4.y >> 9], 1);
        atomicAdd(&hist[d4.z >> 9], 1);
        atomicAdd(&hist[d4.w >> 9], 1);
    }
    __syncthreads();
    if (tid < NBUK && hist[tid] != 0) atomicAdd(&buk_cnt[tid], hist[tid]);
}

// scan 196 bucket counts -> buk_off (exclusive), init bcur
__global__ __launch_bounds__(256) void buk_scan_k(const int* __restrict__ buk_cnt,
                                                  int* __restrict__ buk_off,
                                                  int* __restrict__ bcur) {
    __shared__ int sm[256];
    int t = threadIdx.x;
    int v = (t < NBUK) ? buk_cnt[t] : 0;
    sm[t] = v;
    __syncthreads();
    for (int s = 1; s < 256; s <<= 1) {
        int add = (t >= s) ? sm[t - s] : 0;
        __syncthreads();
        sm[t] += add;
        __syncthreads();
    }
    if (t < NBUK) {
        int excl = sm[t] - v;
        buk_off[t] = excl;
        bcur[t] = excl;
    }
    if (t == 0) buk_off[NBUK] = N_EDGES;
}

// ---------------- coarse partition: group edges by 512-node bucket ----------------

__global__ __launch_bounds__(256) void coarse_k(const int* __restrict__ src,
                                                const int* __restrict__ dst,
                                                int* __restrict__ bcur,
                                                int2* __restrict__ pairs) {
    __shared__ int hist[NBUK + 4], loff[NBUK + 4], cur[NBUK + 4], gbase[NBUK + 4];
    __shared__ int sc[256];
    __shared__ int2 stage[CB];  // 32 KB
    int tid = threadIdx.x;
    int eb = blockIdx.x * CB;
    int nvalid = N_EDGES - eb;
    if (nvalid > CB) nvalid = CB;

    if (tid < NBUK) hist[tid] = 0;
    __syncthreads();

    int4 s4[4], d4[4];
    #pragma unroll
    for (int q = 0; q < 4; ++q) {
        int e4 = (eb >> 2) + tid + q * 256;
        if (e4 * 4 < N_EDGES) {
            s4[q] = ((const int4*)src)[e4];
            d4[q] = ((const int4*)dst)[e4];
        } else {
            d4[q] = make_int4(-1, -1, -1, -1);
            s4[q] = make_int4(0, 0, 0, 0);
        }
    }
    #pragma unroll
    for (int q = 0; q < 4; ++q) {
        if (d4[q].x >= 0) {
            atomicAdd(&hist[d4[q].x >> 9], 1);
            atomicAdd(&hist[d4[q].y >> 9], 1);
            atomicAdd(&hist[d4[q].z >> 9], 1);
            atomicAdd(&hist[d4[q].w >> 9], 1);
        }
    }
    __syncthreads();

    int v = (tid < NBUK) ? hist[tid] : 0;
    sc[tid] = v;
    __syncthreads();
    for (int s = 1; s < 256; s <<= 1) {
        int add = (tid >= s) ? sc[tid - s] : 0;
        __syncthreads();
        sc[tid] += add;
        __syncthreads();
    }
    if (tid < NBUK) {
        int excl = sc[tid] - v;
        loff[tid] = excl;
        cur[tid] = excl;
        gbase[tid] = atomicAdd(&bcur[tid], v);
    }
    __syncthreads();

    #pragma unroll
    for (int q = 0; q < 4; ++q) {
        if (d4[q].x >= 0) {
            int b, r;
            b = d4[q].x >> 9; r = atomicAdd(&cur[b], 1); stage[r] = make_int2(s4[q].x, d4[q].x);
            b = d4[q].y >> 9; r = atomicAdd(&cur[b], 1); stage[r] = make_int2(s4[q].y, d4[q].y);
            b = d4[q].z >> 9; r = atomicAdd(&cur[b], 1); stage[r] = make_int2(s4[q].z, d4[q].z);
            b = d4[q].w >> 9; r = atomicAdd(&cur[b], 1); stage[r] = make_int2(s4[q].w, d4[q].w);
        }
    }
    __syncthreads();

    for (int i = tid; i < nvalid; i += 256) {
        int2 p = stage[i];
        int b = p.y >> 9;
        pairs[gbase[b] + (i - loff[b])] = p;
    }
}

// ---------------- fine: per-bucket degree count (LDS) + dinv + row_ptr + placement ----------------

__global__ __launch_bounds__(256) void fine2_k(const int2* __restrict__ pairs,
                                               const int* __restrict__ buk_off,
                                               int* __restrict__ csr_src,
                                               int* __restrict__ row_ptr,
                                               float* __restrict__ dinv) {
    __shared__ int cnt[512];
    __shared__ int psc[256];
    __shared__ int cur[512];
    int b = blockIdx.x;
    int node0 = b * 512;
    int nn = N_NODES - node0;
    if (nn > 512) nn = 512;
    int tid = threadIdx.x;

    cnt[tid] = 0; cnt[tid + 256] = 0;
    __syncthreads();

    int e0 = buk_off[b];
    int e1 = buk_off[b + 1];

    for (int e = e0 + tid; e < e1; e += 256)
        atomicAdd(&cnt[pairs[e].y - node0], 1);
    __syncthreads();

    int c0 = cnt[2 * tid], c1 = cnt[2 * tid + 1];
    int p = c0 + c1;
    psc[tid] = p;
    __syncthreads();
    for (int s = 1; s < 256; s <<= 1) {
        int add = (tid >= s) ? psc[tid - s] : 0;
        __syncthreads();
        psc[tid] += add;
        __syncthreads();
    }
    int excl = psc[tid] - p;
    int g0 = e0 + excl;
    int g1 = g0 + c0;
    cur[2 * tid] = g0;
    cur[2 * tid + 1] = g1;
    if (2 * tid < nn) {
        row_ptr[node0 + 2 * tid] = g0;
        dinv[node0 + 2 * tid] = 1.0f / sqrtf((float)(c0 + 1));
    }
    if (2 * tid + 1 < nn) {
        row_ptr[node0 + 2 * tid + 1] = g1;
        dinv[node0 + 2 * tid + 1] = 1.0f / sqrtf((float)(c1 + 1));
    }
    if (b == NBUK - 1 && tid == 0) row_ptr[N_NODES] = N_EDGES;
    __syncthreads();

    for (int e = e0 + tid; e < e1; e += 256) {
        int2 pr = pairs[e];
        int pos = atomicAdd(&cur[pr.y - node0], 1);
        csr_src[pos] = pr.x;
    }
}

// ---------------- register-tiled GEMM 1: hws_h = fp16((x @ W1) * dinv[row]) ----------------

__global__ __launch_bounds__(256) void gemm1_tiled_k(const float* __restrict__ x,
                                                     const float* __restrict__ W,
                                                     const float* __restrict__ dinv,
                                                     __half* __restrict__ hws_h) {
    __shared__ float Ws[64][64];
    __shared__ float xt[64][68];
    int tid = threadIdx.x;
    int row0 = blockIdx.x * TM;
    int rgrp4 = (tid >> 4) * 4;
    int cgrp4 = (tid & 15) * 4;

    float acc[4][4];
    #pragma unroll
    for (int r = 0; r < 4; ++r)
        #pragma unroll
        for (int c = 0; c < 4; ++c) acc[r][c] = 0.0f;

    for (int k0 = 0; k0 < IN_FEAT; k0 += 64) {
        #pragma unroll
        for (int i = 0; i < 4; ++i) {
            int f4 = tid + i * 256;
            int kk = f4 >> 4, c4 = (f4 & 15) * 4;
            *(float4*)&Ws[kk][c4] = *(const float4*)&W[(size_t)(k0 + kk) * HIDDEN + c4];
        }
        #pragma unroll
        for (int i = 0; i < 4; ++i) {
            int f4 = tid + i * 256;
            int rr = f4 >> 4, kq = (f4 & 15) * 4;
            int row = row0 + rr;
            if (row >= N_NODES) row = N_NODES - 1;
            float4 v = *(const float4*)&x[(size_t)row * IN_FEAT + k0 + kq];
            xt[kq + 0][rr] = v.x; xt[kq + 1][rr] = v.y;
            xt[kq + 2][rr] = v.z; xt[kq + 3][rr] = v.w;
        }
        __syncthreads();

        #pragma unroll 16
        for (int kk = 0; kk < 64; ++kk) {
            float4 a = *(const float4*)&xt[kk][rgrp4];
            float4 b = *(const float4*)&Ws[kk][cgrp4];
            acc[0][0] += a.x * b.x; acc[0][1] += a.x * b.y; acc[0][2] += a.x * b.z; acc[0][3] += a.x * b.w;
            acc[1][0] += a.y * b.x; acc[1][1] += a.y * b.y; acc[1][2] += a.y * b.z; acc[1][3] += a.y * b.w;
            acc[2][0] += a.z * b.x; acc[2][1] += a.z * b.y; acc[2][2] += a.z * b.z; acc[2][3] += a.z * b.w;
            acc[3][0] += a.w * b.x; acc[3][1] += a.w * b.y; acc[3][2] += a.w * b.z; acc[3][3] += a.w * b.w;
        }
        __syncthreads();
    }

    #pragma unroll
    for (int r = 0; r < 4; ++r) {
        int row = row0 + rgrp4 + r;
        if (row < N_NODES) {
            float dn = dinv[row];
            __half2* ph = (__half2*)&hws_h[(size_t)row * HIDDEN + cgrp4];
            ph[0] = __floats2half2_rn(acc[r][0] * dn, acc[r][1] * dn);
            ph[1] = __floats2half2_rn(acc[r][2] * dn, acc[r][3] * dn);
        }
    }
}

// ---------------- register-tiled GEMM 2: hws_h = fp16((relu(agg) @ W2) * dinv[row]) ----------------

__global__ __launch_bounds__(256) void gemm2_tiled_k(const float* __restrict__ agg,
                                                     const float* __restrict__ W,
                                                     const float* __restrict__ dinv,
                                                     __half* __restrict__ hws_h) {
    __shared__ float Ws[64][64];
    __shared__ float xt[64][68];
    int tid = threadIdx.x;
    int row0 = blockIdx.x * TM;
    int rgrp4 = (tid >> 4) * 4;
    int cgrp4 = (tid & 15) * 4;

    #pragma unroll
    for (int i = 0; i < 4; ++i) {
        int f4 = tid + i * 256;
        int kk = f4 >> 4, c4 = (f4 & 15) * 4;
        *(float4*)&Ws[kk][c4] = *(const float4*)&W[(size_t)kk * HIDDEN + c4];
    }
    #pragma unroll
    for (int i = 0; i < 4; ++i) {
        int f4 = tid + i * 256;
        int rr = f4 >> 4, kq = (f4 & 15) * 4;
        int row = row0 + rr;
        if (row >= N_NODES) row = N_NODES - 1;
        float4 v = *(const float4*)&agg[(size_t)row * HIDDEN + kq];
        xt[kq + 0][rr] = fmaxf(v.x, 0.f); xt[kq + 1][rr] = fmaxf(v.y, 0.f);
        xt[kq + 2][rr] = fmaxf(v.z, 0.f); xt[kq + 3][rr] = fmaxf(v.w, 0.f);
    }
    __syncthreads();

    float acc[4][4];
    #pragma unroll
    for (int r = 0; r < 4; ++r)
        #pragma unroll
        for (int c = 0; c < 4; ++c) acc[r][c] = 0.0f;

    #pragma unroll 16
    for (int kk = 0; kk < 64; ++kk) {
        float4 a = *(const float4*)&xt[kk][rgrp4];
        float4 b = *(const float4*)&Ws[kk][cgrp4];
        acc[0][0] += a.x * b.x; acc[0][1] += a.x * b.y; acc[0][2] += a.x * b.z; acc[0][3] += a.x * b.w;
        acc[1][0] += a.y * b.x; acc[1][1] += a.y * b.y; acc[1][2] += a.y * b.z; acc[1][3] += a.y * b.w;
        acc[2][0] += a.z * b.x; acc[2][1] += a.z * b.y; acc[2][2] += a.z * b.z; acc[2][3] += a.z * b.w;
        acc[3][0] += a.w * b.x; acc[3][1] += a.w * b.y; acc[3][2] += a.w * b.z; acc[3][3] += a.w * b.w;
    }

    #pragma unroll
    for (int r = 0; r < 4; ++r) {
        int row = row0 + rgrp4 + r;
        if (row < N_NODES) {
            float dn = dinv[row];
            __half2* ph = (__half2*)&hws_h[(size_t)row * HIDDEN + cgrp4];
            ph[0] = __floats2half2_rn(acc[r][0] * dn, acc[r][1] * dn);
            ph[1] = __floats2half2_rn(acc[r][2] * dn, acc[r][3] * dn);
        }
    }
}

// ---------------- CSR pull: agg[d] = b + dinv[d]*(hws[d] + sum_in hws[s]) ----------------
// one wave per node, lane = channel, fp16 rows. Wave-uniform scalar index loads.
// SINGLE clamped-8 main loop: indices clamped to end-1, weight 0/1 folded into FMA,
// so all 8 gathers per round are unconditional and in flight -> rounds = ceil(deg/8).

__global__ __launch_bounds__(256) void pull_k(const int* __restrict__ row_ptr,
                                              const int* __restrict__ csr_src,
                                              const float* __restrict__ dinv,
                                              const __half* __restrict__ hws_h,
                                              const float* __restrict__ b,
                                              float* __restrict__ agg) {
    int node = (blockIdx.x * 256 + threadIdx.x) >> 6;
    int lane = threadIdx.x & 63;
    if (node >= N_NODES) return;

    int start = row_ptr[node];
    int end   = row_ptr[node + 1];

    float a0 = __half2float(hws_h[(size_t)node * HIDDEN + lane]);  // self-loop term
    float a1 = 0.f, a2 = 0.f, a3 = 0.f, a4 = 0.f, a5 = 0.f, a6 = 0.f, a7 = 0.f;

    int last = end - 1;
    for (int i = start; i < end; i += 8) {
        int e0 = i + 0, e1 = i + 1, e2 = i + 2, e3 = i + 3;
        int e4 = i + 4, e5 = i + 5, e6 = i + 6, e7 = i + 7;
        // clamp (wave-uniform scalar selects)
        int c0 = e0 < end ? e0 : last;  int c1 = e1 < end ? e1 : last;
        int c2 = e2 < end ? e2 : last;  int c3 = e3 < end ? e3 : last;
        int c4 = e4 < end ? e4 : last;  int c5 = e5 < end ? e5 : last;
        int c6 = e6 < end ? e6 : last;  int c7 = e7 < end ? e7 : last;
        int s0 = csr_src[c0]; int s1 = csr_src[c1];
        int s2 = csr_src[c2]; int s3 = csr_src[c3];
        int s4 = csr_src[c4]; int s5 = csr_src[c5];
        int s6 = csr_src[c6]; int s7 = csr_src[c7];
        float w1 = e1 < end ? 1.f : 0.f;  float w2 = e2 < end ? 1.f : 0.f;
        float w3 = e3 < end ? 1.f : 0.f;  float w4 = e4 < end ? 1.f : 0.f;
        float w5 = e5 < end ? 1.f : 0.f;  float w6 = e6 < end ? 1.f : 0.f;
        float w7 = e7 < end ? 1.f : 0.f;
        a0 +=      __half2float(hws_h[(size_t)s0 * HIDDEN + lane]);   // e0 always valid
        a1 += w1 * __half2float(hws_h[(size_t)s1 * HIDDEN + lane]);
        a2 += w2 * __half2float(hws_h[(size_t)s2 * HIDDEN + lane]);
        a3 += w3 * __half2float(hws_h[(size_t)s3 * HIDDEN + lane]);
        a4 += w4 * __half2float(hws_h[(size_t)s4 * HIDDEN + lane]);
        a5 += w5 * __half2float(hws_h[(size_t)s5 * HIDDEN + lane]);
        a6 += w6 * __half2float(hws_h[(size_t)s6 * HIDDEN + lane]);
        a7 += w7 * __half2float(hws_h[(size_t)s7 * HIDDEN + lane]);
    }

    float sum = ((a0 + a1) + (a2 + a3)) + ((a4 + a5) + (a6 + a7));
    agg[(size_t)node * HIDDEN + lane] = b[lane] + dinv[node] * sum;
}

// ---------------- final: out = relu(agg) @ Wl + bl ----------------

__global__ __launch_bounds__(256) void final_k(const float* __restrict__ agg,
                                               const float* __restrict__ Wl,
                                               const float* __restrict__ bl,
                                               float* __restrict__ out) {
    __shared__ float Ws[HIDDEN * N_CLASSES];
    __shared__ float hs[16][HIDDEN + 1];
    int tid = threadIdx.x;

    if (tid < HIDDEN * N_CLASSES / 4) ((float4*)Ws)[tid] = ((const float4*)Wl)[tid];

    int row0 = blockIdx.x * 16;
    for (int i = tid; i < 16 * HIDDEN; i += 256) {
        int rr = i >> 6;
        int kk = i & 63;
        hs[rr][kk] = fmaxf(agg[(size_t)(row0 + rr) * HIDDEN + kk], 0.0f);
    }
    __syncthreads();

    int col = tid & 15;
    int r = tid >> 4;
    float acc = bl[col];
    #pragma unroll
    for (int k = 0; k < HIDDEN; ++k)
        acc += hs[r][k] * Ws[k * N_CLASSES + col];
    out[(size_t)(row0 + r) * N_CLASSES + col] = acc;
}

// ---------------- launch ----------------

extern "C" void kernel_launch(void* const* d_in, const int* in_sizes, int n_in,
                              void* d_out, int out_size, void* d_ws, size_t ws_size,
                              hipStream_t stream) {
    const float* x  = (const float*)d_in[0];
    const int*   ei = (const int*)d_in[1];
    const float* W1 = (const float*)d_in[2];
    const float* b1 = (const float*)d_in[3];
    const float* W2 = (const float*)d_in[4];
    const float* b2 = (const float*)d_in[5];
    const float* Wl = (const float*)d_in[6];
    const float* bl = (const float*)d_in[7];
    float* out = (float*)d_out;

    const int* src = ei;
    const int* dst = ei + N_EDGES;

    __half* hws_h  = (__half*)d_ws;                              // N*64 halves (12.8 MB)
    float* agg     = (float*)(hws_h + (size_t)N_NODES * HIDDEN); // N*64 floats (25.6 MB)
    int2*  pairs   = (int2*)agg;                                 // aliases agg (dead before pull writes agg)
    int*   csr_src = (int*)(agg + (size_t)N_NODES * HIDDEN);     // E
    float* dinv    = (float*)(csr_src + N_EDGES);                // N
    int*   row_ptr = (int*)(dinv + N_NODES);                     // N+4
    int*   buk_cnt = row_ptr + N_NODES + 4;                      // 200
    int*   buk_off = buk_cnt + 200;                              // 200
    int*   bcur    = buk_off + 200;                              // 200

    // --- CSR build (degree counting confined to LDS) ---
    zero_buk_k<<<1, 256, 0, stream>>>(buk_cnt);
    bukhist_k<<<NHB, 256, 0, stream>>>(dst, buk_cnt);
    buk_scan_k<<<1, 256, 0, stream>>>(buk_cnt, buk_off, bcur);
    coarse_k<<<NCB, 256, 0, stream>>>(src, dst, bcur, pairs);
    fine2_k<<<NBUK, 256, 0, stream>>>(pairs, buk_off, csr_src, row_ptr, dinv);

    // --- layer 1 ---
    gemm1_tiled_k<<<GBLK, 256, 0, stream>>>(x, W1, dinv, hws_h);
    pull_k<<<(N_NODES * 64 + 255) / 256, 256, 0, stream>>>(row_ptr, csr_src, dinv,
                                                           hws_h, b1, agg);

    // --- layer 2 ---
    gemm2_tiled_k<<<GBLK, 256, 0, stream>>>(agg, W2, dinv, hws_h);
    pull_k<<<(N_NODES * 64 + 255) / 256, 256, 0, stream>>>(row_ptr, csr_src, dinv,
                                                           hws_h, b2, agg);

    // --- classifier head ---
    final_k<<<N_NODES / 16, 256, 0, stream>>>(agg, Wl, bl, out);
}